// Round 1
// baseline (78.121 us; speedup 1.0000x reference)
//
#include <hip/hip_runtime.h>
#include <hip/hip_bf16.h>
#include <math.h>

// One thread per OUTPUT ROW (float4). B points -> 4B threads.
// Consecutive threads write consecutive float4 -> perfectly coalesced stores.
// The 4 threads of a point redundantly compute the (cheap) per-point math;
// input reads broadcast within cache lines, so HBM fetch stays ~48 MB.

#define TRANSLATION_SCALE 1.0f
#define ROTATION_SCALE    0.1f
#define EPS               1e-5f

__global__ __launch_bounds__(256) void lie_se3_kernel(
    const float* __restrict__ uv, float* __restrict__ out, int n_points)
{
    int j = blockIdx.x * blockDim.x + threadIdx.x;     // row index, [0, 4*n)
    int total = n_points * 4;
    if (j >= total) return;

    int p = j >> 2;      // point index
    int r = j & 3;       // row within the 4x4

    float x  = uv[3 * p + 0] * TRANSLATION_SCALE;
    float y  = uv[3 * p + 1] * TRANSLATION_SCALE;
    float wz = uv[3 * p + 2] * ROTATION_SCALE;

    float th2 = wz * wz;
    float th  = fabsf(wz);          // sqrt(wz^2)

    float s, c;
    __sincosf(th, &s, &c);

    float A  = s / (th + EPS);                  // sin_div
    float Bc = (1.0f - c) / (th2 + EPS);        // one_minus_cos_div
    float Cc = (1.0f - A) / (th2 + EPS);        // one_minus_A_div

    // R = I + skew*A + skew^2*Bc ; skew^2 = diag(-wz^2, -wz^2, 0)
    float ca = 1.0f - th2 * Bc;     // R00 = R11
    float sa = wz * A;              // R10 = -R01

    // V = I + skew*Bc + skew^2*Cc
    float vc = 1.0f - th2 * Cc;
    float vs = wz * Bc;

    // t = V @ (x, y, 0)
    float t0 = vc * x - vs * y;
    float t1 = vs * x + vc * y;

    float4 o;
    if (r == 0)      o = make_float4(  ca, -sa, 0.0f, t0 );
    else if (r == 1) o = make_float4(  sa,  ca, 0.0f, t1 );
    else if (r == 2) o = make_float4(0.0f, 0.0f, 1.0f, 0.0f);
    else             o = make_float4(0.0f, 0.0f, 0.0f, 1.0f);

    reinterpret_cast<float4*>(out)[j] = o;
}

extern "C" void kernel_launch(void* const* d_in, const int* in_sizes, int n_in,
                              void* d_out, int out_size, void* d_ws, size_t ws_size,
                              hipStream_t stream) {
    const float* uv = (const float*)d_in[0];
    float* out = (float*)d_out;

    int n_points = in_sizes[0] / 3;          // uv is [B,3]
    int total_rows = n_points * 4;           // one thread per float4 row

    const int block = 256;
    int grid = (total_rows + block - 1) / block;

    lie_se3_kernel<<<grid, block, 0, stream>>>(uv, out, n_points);
}

// Round 3
// 75.223 us; speedup vs baseline: 1.0385x; 1.0385x over previous
//
#include <hip/hip_runtime.h>
#include <hip/hip_bf16.h>
#include <math.h>

// One thread per OUTPUT ROW (native float4). B points -> 4B threads.
// Branchless row selection -> a single fully-populated (64/64 lanes) float4
// store per wave-instruction, consecutive threads -> consecutive float4:
// perfectly coalesced global_store_dwordx4. Nontemporal hints on the 256 MB
// write-once output stream (and read-once input) to avoid L2/L3 pollution.
// NOTE: __builtin_nontemporal_store needs a NATIVE vector type, not HIP's
// float4 class -> use ext_vector_type.

#define TRANSLATION_SCALE 1.0f
#define ROTATION_SCALE    0.1f
#define EPS               1e-5f

typedef float f32x4 __attribute__((ext_vector_type(4)));

__global__ __launch_bounds__(256) void lie_se3_kernel(
    const float* __restrict__ uv, float* __restrict__ out, int n_points)
{
    int j = blockIdx.x * blockDim.x + threadIdx.x;     // row index, [0, 4*n)
    int total = n_points * 4;
    if (j >= total) return;

    int p = j >> 2;      // point index
    int r = j & 3;       // row within the 4x4

    float x  = __builtin_nontemporal_load(&uv[3 * p + 0]) * TRANSLATION_SCALE;
    float y  = __builtin_nontemporal_load(&uv[3 * p + 1]) * TRANSLATION_SCALE;
    float wz = __builtin_nontemporal_load(&uv[3 * p + 2]) * ROTATION_SCALE;

    float th2 = wz * wz;
    float th  = fabsf(wz);          // sqrt(wz^2)

    float s, c;
    __sincosf(th, &s, &c);

    float A  = s / (th + EPS);                  // sin_div
    float Bc = (1.0f - c) / (th2 + EPS);        // one_minus_cos_div
    float Cc = (1.0f - A) / (th2 + EPS);        // one_minus_A_div

    // R = I + skew*A + skew^2*Bc ; skew^2 = diag(-wz^2, -wz^2, 0)
    float ca = 1.0f - th2 * Bc;     // R00 = R11
    float sa = wz * A;              // R10 = -R01

    // V = I + skew*Bc + skew^2*Cc
    float vc = 1.0f - th2 * Cc;
    float vs = wz * Bc;

    // t = V @ (x, y, 0)
    float t0 = vc * x - vs * y;
    float t1 = vs * x + vc * y;

    // Branchless row build (v_cndmask, no divergent store paths):
    // r==0: [ ca, -sa, 0, t0 ]
    // r==1: [ sa,  ca, 0, t1 ]
    // r==2: [  0,   0, 1,  0 ]
    // r==3: [  0,   0, 0,  1 ]
    bool r0 = (r == 0), r1 = (r == 1), r2 = (r == 2), r3 = (r == 3);

    f32x4 o;
    o.x = r0 ? ca : (r1 ? sa : 0.0f);
    o.y = r0 ? -sa : (r1 ? ca : 0.0f);
    o.z = r2 ? 1.0f : 0.0f;
    o.w = r0 ? t0 : (r1 ? t1 : (r3 ? 1.0f : 0.0f));

    __builtin_nontemporal_store(o, reinterpret_cast<f32x4*>(out) + j);
}

extern "C" void kernel_launch(void* const* d_in, const int* in_sizes, int n_in,
                              void* d_out, int out_size, void* d_ws, size_t ws_size,
                              hipStream_t stream) {
    const float* uv = (const float*)d_in[0];
    float* out = (float*)d_out;

    int n_points = in_sizes[0] / 3;          // uv is [B,3]
    int total_rows = n_points * 4;           // one thread per float4 row

    const int block = 256;
    int grid = (total_rows + block - 1) / block;

    lie_se3_kernel<<<grid, block, 0, stream>>>(uv, out, n_points);
}

// Round 4
// 49.891 us; speedup vs baseline: 1.5658x; 1.5078x over previous
//
#include <hip/hip_runtime.h>
#include <hip/hip_bf16.h>
#include <math.h>

// One thread per POINT (4x fewer waves than thread-per-row): each wave now
// covers 64 points instead of 16, cutting total VALU issue ~4x. The four
// output rows per point are reassembled via a tiny LDS bounce (only the 4
// non-constant values {ca, sa, t0, t1} per point; rows 2,3 are constants),
// so global stores remain one perfectly-coalesced float4 per thread.
// LDS stride 5 floats -> worst-case 2-way bank aliasing (free); the 4 lanes
// sharing a point read the same address (broadcast, conflict-free).
// Divides use v_rcp_f32 (tolerance 0.1075 >> rcp error).

#define TRANSLATION_SCALE 1.0f
#define ROTATION_SCALE    0.1f
#define EPS               1e-5f

typedef float f32x4 __attribute__((ext_vector_type(4)));

__global__ __launch_bounds__(256) void lie_se3_kernel(
    const float* __restrict__ uv, float* __restrict__ out, int n_points)
{
    __shared__ float sh[256 * 5];

    const int t = threadIdx.x;
    const int p = blockIdx.x * 256 + t;          // this thread's point

    float x = 0.0f, y = 0.0f, wz = 0.0f;
    if (p < n_points) {
        x  = uv[3 * p + 0] * TRANSLATION_SCALE;
        y  = uv[3 * p + 1] * TRANSLATION_SCALE;
        wz = uv[3 * p + 2] * ROTATION_SCALE;
    }

    float th2 = wz * wz;
    float th  = fabsf(wz);

    float s, c;
    __sincosf(th, &s, &c);

    float rth  = __builtin_amdgcn_rcpf(th  + EPS);
    float rth2 = __builtin_amdgcn_rcpf(th2 + EPS);

    float A  = s * rth;                 // sin_div
    float Bc = (1.0f - c) * rth2;       // one_minus_cos_div
    float Cc = (1.0f - A) * rth2;       // one_minus_A_div

    float ca = 1.0f - th2 * Bc;         // R00 = R11
    float sa = wz * A;                  // R10 = -R01
    float vc = 1.0f - th2 * Cc;
    float vs = wz * Bc;

    float t0 = vc * x - vs * y;
    float t1 = vs * x + vc * y;

    sh[t * 5 + 0] = ca;
    sh[t * 5 + 1] = sa;
    sh[t * 5 + 2] = t0;
    sh[t * 5 + 3] = t1;
    __syncthreads();

    // Output: this block owns float4 rows [blockIdx*1024, +1024).
    // Thread t, iteration it -> local float4 row f4 = it*256 + t,
    // which is row sel=t&3 of local point pl = f4>>2 = it*64 + (t>>2).
    const long base4 = (long)blockIdx.x * 1024;
    const int  sel   = t & 3;

    #pragma unroll
    for (int it = 0; it < 4; ++it) {
        int pl = it * 64 + (t >> 2);

        float ca_ = sh[pl * 5 + 0];                  // broadcast within 4-lane group
        float sa_ = sh[pl * 5 + 1];
        float tx_ = sh[pl * 5 + 2 + (sel & 1)];      // t0 for sel0, t1 for sel1

        // rows: sel0 [ca,-sa,0,t0]  sel1 [sa,ca,0,t1]  sel2 [0,0,1,0]  sel3 [0,0,0,1]
        f32x4 o;
        o.x = (sel == 0) ?  ca_ : (sel == 1) ? sa_ : 0.0f;
        o.y = (sel == 0) ? -sa_ : (sel == 1) ? ca_ : 0.0f;
        o.z = (sel == 2) ? 1.0f : 0.0f;
        o.w = (sel <  2) ?  tx_ : (sel == 3) ? 1.0f : 0.0f;

        if (blockIdx.x * 256 + pl < n_points)
            __builtin_nontemporal_store(o, reinterpret_cast<f32x4*>(out) + base4 + it * 256 + t);
    }
}

extern "C" void kernel_launch(void* const* d_in, const int* in_sizes, int n_in,
                              void* d_out, int out_size, void* d_ws, size_t ws_size,
                              hipStream_t stream) {
    const float* uv = (const float*)d_in[0];
    float* out = (float*)d_out;

    int n_points = in_sizes[0] / 3;              // uv is [B,3]
    int grid = (n_points + 255) / 256;

    lie_se3_kernel<<<grid, 256, 0, stream>>>(uv, out, n_points);
}